// Round 3
// baseline (193.684 us; speedup 1.0000x reference)
//
#include <hip/hip_runtime.h>
#include <stdint.h>

#define B_TOT 16384
#define IN_DIM 128
#define H1 256
#define H2 128
#define NC 10

// LDS layout: W2T rows 0..255 = data, row 256 = zeros (dummy target).
//             WoT rows 0..127 = data, row 128 = zeros.
#define W2T_ROWS 257
#define WOT_ROWS 129
#define LDS_FLOATS (W2T_ROWS * H2 + WOT_ROWS * NC)

// ---------------------------------------------------------------------------
// Kernel A: cur1[b][n] = sum_k x[b][k]*W1[n][k] + b1[n]
// ---------------------------------------------------------------------------
__global__ __launch_bounds__(256) void gemm1_kernel(
    const float* __restrict__ x, const float* __restrict__ W1,
    const float* __restrict__ b1, float* __restrict__ cur1) {
  __shared__ float xs[16 * 128];
  const int tid = threadIdx.x;
  const long row0 = (long)blockIdx.x * 16;

  const float4* xt = (const float4*)(x + row0 * IN_DIM);
  float4* xs4 = (float4*)xs;
  xs4[tid] = xt[tid];
  xs4[tid + 256] = xt[tid + 256];
  __syncthreads();

  const int n = tid;
  float acc[16];
#pragma unroll
  for (int r = 0; r < 16; ++r) acc[r] = 0.f;

  const float* wrow = W1 + n * IN_DIM;
  for (int k0 = 0; k0 < IN_DIM; k0 += 4) {
    const float4 wv = *(const float4*)(wrow + k0);
#pragma unroll
    for (int r = 0; r < 16; ++r) {
      const float4 xv = *(const float4*)(xs + r * IN_DIM + k0);
      acc[r] = fmaf(wv.x, xv.x, acc[r]);
      acc[r] = fmaf(wv.y, xv.y, acc[r]);
      acc[r] = fmaf(wv.z, xv.z, acc[r]);
      acc[r] = fmaf(wv.w, xv.w, acc[r]);
    }
  }
  const float bias = b1[n];
#pragma unroll
  for (int r = 0; r < 16; ++r)
    cur1[(row0 + r) * H1 + n] = acc[r] + bias;
}

// ---------------------------------------------------------------------------
// Kernel A2: global transpose of W2 / Wo into workspace.
// ---------------------------------------------------------------------------
__global__ __launch_bounds__(1024) void transpose_kernel(
    const float* __restrict__ W2, const float* __restrict__ Wo,
    float* __restrict__ W2T, float* __restrict__ WoT) {
  const int idx = blockIdx.x * 1024 + threadIdx.x;
  if (idx < H2 * H1) {
    const int o = idx >> 8;
    const int j = idx & 255;
    W2T[j * H2 + o] = W2[idx];
  } else {
    const int k = idx - H2 * H1;
    if (k < NC * H2) {
      const int o = k >> 7;
      const int j = k & 127;
      WoT[j * NC + o] = Wo[k];
    }
  }
}

// ---------------------------------------------------------------------------
// Sparse-extract helpers (wave-uniform masks). Dummy slots point at the LDS
// zero row; adding 0.0f is exact, so summation order/values stay bit-exact.
// ---------------------------------------------------------------------------
__device__ __forceinline__ const float* ext_pair(unsigned long long& m,
                                                 const float* base,
                                                 const float* z) {
  if (m) {
    const int j = __builtin_ctzll(m);
    m &= m - 1;
    return base + j * H2;
  }
  return z;
}

__device__ __forceinline__ const float* ext_out(unsigned long long& m,
                                                const float* wot, int off,
                                                int lo, const float* z) {
  if (m) {
    const int j = __builtin_ctzll(m);
    m &= m - 1;
    return wot + (2 * j + off) * NC + lo;
  }
  return z;
}

// ---------------------------------------------------------------------------
// Kernel B: fused 20-step recurrent SNN. 256 persistent blocks (1/CU),
// 16 waves/block, 4 batch rows per wave (sequential).
// Sparse currents via ballot masks; 4-deep batched + value-pipelined LDS
// reads (zero-row dummies keep the sum bit-exact vs. the dense reference).
// ---------------------------------------------------------------------------
__global__ __launch_bounds__(1024) void snn_kernel(
    const float* __restrict__ cur1,
    const float* __restrict__ W2Tg, const float* __restrict__ WoTg,
    const float* __restrict__ W2, const float* __restrict__ Wo,
    const float* __restrict__ x, const float* __restrict__ W1,
    const float* __restrict__ b1,
    const float* __restrict__ b2, const float* __restrict__ bo,
    const int* __restrict__ nsp, float* __restrict__ out) {
  extern __shared__ float lds[];
  float* w2t = lds;                       // [257][128]
  float* wot = lds + W2T_ROWS * H2;       // [129][10]

  const int tid = threadIdx.x;
  if (W2Tg != nullptr) {
    float4* dst = (float4*)w2t;
    const float4* src = (const float4*)W2Tg;
#pragma unroll
    for (int i = 0; i < 8; ++i) dst[tid + i * 1024] = src[tid + i * 1024];
    if (tid < 320) ((float4*)wot)[tid] = ((const float4*)WoTg)[tid];
  } else {
    for (int idx = tid; idx < H2 * H1; idx += 1024) {
      const int o = idx >> 8;
      const int j = idx & 255;
      w2t[j * H2 + o] = W2[idx];
    }
    for (int idx = tid; idx < NC * H2; idx += 1024) {
      const int o = idx >> 7;
      const int j = idx & 127;
      wot[j * NC + o] = Wo[idx];
    }
  }
  // zero rows (dummy targets)
  if (tid < 32) ((float4*)(w2t + 256 * H2))[tid] = make_float4(0.f, 0.f, 0.f, 0.f);
  if (tid < NC) wot[128 * NC + tid] = 0.f;
  __syncthreads();

  const int w = tid >> 6;
  const int l = tid & 63;
  const int lo = (l < NC) ? l : 0;
  const float bb0 = b2[2 * l];
  const float bb1 = b2[2 * l + 1];
  const float bol = bo[lo];
  const float* w2l = w2t + 2 * l;               // lane's output pair
  const float* zl2 = w2t + 256 * H2 + 2 * l;    // lane's zero-pair
  const float* zo = wot + 128 * NC + lo;        // lane's zero out-entry
  const int nsteps = *nsp;

  for (int r = 0; r < 4; ++r) {
    const long b = (long)blockIdx.x * 64 + w * 4 + r;

    float c[4];
    if (cur1 != nullptr) {
#pragma unroll
      for (int i = 0; i < 4; ++i) c[i] = cur1[b * H1 + i * 64 + l];
    } else {
      const float* xr = x + b * IN_DIM;
#pragma unroll
      for (int i = 0; i < 4; ++i) {
        const int n = i * 64 + l;
        const float* wr = W1 + n * IN_DIM;
        float a = 0.f;
        for (int k = 0; k < IN_DIM; k += 4) {
          const float4 wv = *(const float4*)(wr + k);
          const float4 xv = *(const float4*)(xr + k);
          a = fmaf(wv.x, xv.x, a);
          a = fmaf(wv.y, xv.y, a);
          a = fmaf(wv.z, xv.z, a);
          a = fmaf(wv.w, xv.w, a);
        }
        c[i] = a + b1[n];
      }
    }

    float m1[4] = {0.f, 0.f, 0.f, 0.f};
    float sp1[4] = {0.f, 0.f, 0.f, 0.f};
    float m2a = 0.f, m2b = 0.f, sp2a = 0.f, sp2b = 0.f;
    float mo = 0.f, spo = 0.f, cnt = 0.f;

    for (int t = 0; t < nsteps; ++t) {
      // ---- layer 1 LIF ----
      unsigned long long mk[4];
#pragma unroll
      for (int i = 0; i < 4; ++i) {
        m1[i] = fmaf(0.5f, m1[i], c[i]) - sp1[i];
        const bool s = m1[i] > 1.0f;
        mk[i] = __ballot(s);
        sp1[i] = s ? 1.0f : 0.0f;
      }

      // ---- cur2 = s1 @ W2^T (+ b2): batched, value-pipelined sparse sum ----
      float a0 = 0.f, a1 = 0.f;
#pragma unroll
      for (int i = 0; i < 4; ++i) {
        unsigned long long m = mk[i];
        if (m == 0ULL) continue;
        const float* base = w2l + (i * 64) * H2;
        const int nb = (__popcll(m) + 3) >> 2;

        const float* q0 = ext_pair(m, base, zl2);
        const float* q1 = ext_pair(m, base, zl2);
        const float* q2 = ext_pair(m, base, zl2);
        const float* q3 = ext_pair(m, base, zl2);
        float2 v0 = *(const float2*)q0;
        float2 v1 = *(const float2*)q1;
        float2 v2 = *(const float2*)q2;
        float2 v3 = *(const float2*)q3;

        for (int k = 1; k < nb; ++k) {
          const float* n0 = ext_pair(m, base, zl2);
          const float* n1 = ext_pair(m, base, zl2);
          const float* n2 = ext_pair(m, base, zl2);
          const float* n3 = ext_pair(m, base, zl2);
          const float2 u0 = *(const float2*)n0;   // batch-k loads issue
          const float2 u1 = *(const float2*)n1;   // before batch-(k-1)
          const float2 u2 = *(const float2*)n2;   // values are consumed
          const float2 u3 = *(const float2*)n3;
          a0 += v0.x; a1 += v0.y;
          a0 += v1.x; a1 += v1.y;
          a0 += v2.x; a1 += v2.y;
          a0 += v3.x; a1 += v3.y;
          v0 = u0; v1 = u1; v2 = u2; v3 = u3;
        }
        a0 += v0.x; a1 += v0.y;
        a0 += v1.x; a1 += v1.y;
        a0 += v2.x; a1 += v2.y;
        a0 += v3.x; a1 += v3.y;
      }
      a0 += bb0;
      a1 += bb1;

      // ---- layer 2 LIF ----
      m2a = fmaf(0.5f, m2a, a0) - sp2a;
      m2b = fmaf(0.5f, m2b, a1) - sp2b;
      const bool sa = m2a > 1.0f;
      const bool sb = m2b > 1.0f;
      unsigned long long mA = __ballot(sa);
      unsigned long long mB = __ballot(sb);
      sp2a = sa ? 1.0f : 0.0f;
      sp2b = sb ? 1.0f : 0.0f;

      // ---- output layer: issue even+odd loads together, add in order ----
      const float* qa0 = ext_out(mA, wot, 0, lo, zo);
      const float* qa1 = ext_out(mA, wot, 0, lo, zo);
      const float* qa2 = ext_out(mA, wot, 0, lo, zo);
      const float* qa3 = ext_out(mA, wot, 0, lo, zo);
      const float* qb0 = ext_out(mB, wot, 1, lo, zo);
      const float* qb1 = ext_out(mB, wot, 1, lo, zo);
      const float* qb2 = ext_out(mB, wot, 1, lo, zo);
      const float* qb3 = ext_out(mB, wot, 1, lo, zo);
      const float va0 = *qa0, va1 = *qa1, va2 = *qa2, va3 = *qa3;
      const float vb0 = *qb0, vb1 = *qb1, vb2 = *qb2, vb3 = *qb3;

      float co = 0.f;
      co += va0; co += va1; co += va2; co += va3;
      while (mA) {  // rare tail (>4 even spikes)
        const int j = __builtin_ctzll(mA);
        mA &= mA - 1;
        co += wot[(2 * j) * NC + lo];
      }
      co += vb0; co += vb1; co += vb2; co += vb3;
      while (mB) {  // rare tail (>4 odd spikes)
        const int j = __builtin_ctzll(mB);
        mB &= mB - 1;
        co += wot[(2 * j + 1) * NC + lo];
      }
      co += bol;

      // ---- output LIF + spike count ----
      mo = fmaf(0.5f, mo, co) - spo;
      const bool so = mo > 1.0f;
      spo = so ? 1.0f : 0.0f;
      cnt += spo;
    }

    if (l < NC) out[b * NC + l] = cnt;
  }
}

// ---------------------------------------------------------------------------
extern "C" void kernel_launch(void* const* d_in, const int* in_sizes, int n_in,
                              void* d_out, int out_size, void* d_ws,
                              size_t ws_size, hipStream_t stream) {
  const float* x  = (const float*)d_in[0];
  const float* W1 = (const float*)d_in[1];
  const float* b1 = (const float*)d_in[2];
  const float* W2 = (const float*)d_in[3];
  const float* b2 = (const float*)d_in[4];
  const float* Wo = (const float*)d_in[5];
  const float* bo = (const float*)d_in[6];
  const int* nsp  = (const int*)d_in[7];
  float* outp = (float*)d_out;

  const size_t cur1_bytes = (size_t)B_TOT * H1 * sizeof(float);
  const size_t w2t_bytes  = (size_t)H1 * H2 * sizeof(float);
  const size_t wot_bytes  = (size_t)H2 * NC * sizeof(float);

  float* cur1 = nullptr;
  float* W2Tg = nullptr;
  float* WoTg = nullptr;

  if (ws_size >= cur1_bytes) {
    cur1 = (float*)d_ws;
    gemm1_kernel<<<B_TOT / 16, 256, 0, stream>>>(x, W1, b1, cur1);
  }
  if (ws_size >= cur1_bytes + w2t_bytes + wot_bytes) {
    W2Tg = (float*)((char*)d_ws + cur1_bytes);
    WoTg = W2Tg + H1 * H2;
    transpose_kernel<<<(H2 * H1 + NC * H2 + 1023) / 1024, 1024, 0, stream>>>(
        W2, Wo, W2Tg, WoTg);
  }

  const size_t ldsB = (size_t)LDS_FLOATS * sizeof(float);  // ~133.5 KB
  hipFuncSetAttribute((const void*)snn_kernel,
                      hipFuncAttributeMaxDynamicSharedMemorySize, (int)ldsB);
  snn_kernel<<<256, 1024, ldsB, stream>>>(cur1, W2Tg, WoTg, W2, Wo, x, W1, b1,
                                          b2, bo, nsp, outp);
}

// Round 4
// 178.953 us; speedup vs baseline: 1.0823x; 1.0823x over previous
//
#include <hip/hip_runtime.h>
#include <stdint.h>

#define B_TOT 16384
#define IN_DIM 128
#define H1 256
#define H2 128
#define NC 10

typedef float v2f __attribute__((ext_vector_type(2)));

// ---------------------------------------------------------------------------
// Kernel A: cur1[b][n] = sum_k x[b][k]*W1[n][k] + b1[n]
// ---------------------------------------------------------------------------
__global__ __launch_bounds__(256) void gemm1_kernel(
    const float* __restrict__ x, const float* __restrict__ W1,
    const float* __restrict__ b1, float* __restrict__ cur1) {
  __shared__ float xs[16 * 128];
  const int tid = threadIdx.x;
  const long row0 = (long)blockIdx.x * 16;

  const float4* xt = (const float4*)(x + row0 * IN_DIM);
  float4* xs4 = (float4*)xs;
  xs4[tid] = xt[tid];
  xs4[tid + 256] = xt[tid + 256];
  __syncthreads();

  const int n = tid;
  float acc[16];
#pragma unroll
  for (int r = 0; r < 16; ++r) acc[r] = 0.f;

  const float* wrow = W1 + n * IN_DIM;
  for (int k0 = 0; k0 < IN_DIM; k0 += 4) {
    const float4 wv = *(const float4*)(wrow + k0);
#pragma unroll
    for (int r = 0; r < 16; ++r) {
      const float4 xv = *(const float4*)(xs + r * IN_DIM + k0);
      acc[r] = fmaf(wv.x, xv.x, acc[r]);
      acc[r] = fmaf(wv.y, xv.y, acc[r]);
      acc[r] = fmaf(wv.z, xv.z, acc[r]);
      acc[r] = fmaf(wv.w, xv.w, acc[r]);
    }
  }
  const float bias = b1[n];
#pragma unroll
  for (int r = 0; r < 16; ++r)
    cur1[(row0 + r) * H1 + n] = acc[r] + bias;
}

// ---------------------------------------------------------------------------
// Kernel A2: global transpose of W2 / Wo into workspace.
// ---------------------------------------------------------------------------
__global__ __launch_bounds__(1024) void transpose_kernel(
    const float* __restrict__ W2, const float* __restrict__ Wo,
    float* __restrict__ W2T, float* __restrict__ WoT) {
  const int idx = blockIdx.x * 1024 + threadIdx.x;
  if (idx < H2 * H1) {
    const int o = idx >> 8;
    const int j = idx & 255;
    W2T[j * H2 + o] = W2[idx];
  } else {
    const int k = idx - H2 * H1;
    if (k < NC * H2) {
      const int o = k >> 7;
      const int j = k & 127;
      WoT[j * NC + o] = Wo[k];
    }
  }
}

// ---------------------------------------------------------------------------
// Kernel B: fused 20-step recurrent SNN. 256 persistent blocks (1/CU),
// 16 waves/block, 4 batch rows per wave.
// Sparse currents via wave-uniform ballot masks. 4-deep load pipeline per
// group with REGISTER-ZERO dummies (no LDS traffic for padding slots);
// summation order is bit-identical to the verified round-2 kernel:
// groups i=0..3 ascending, j ascending within group (zeros interleave but
// add +0.0f exactly), bias last; output layer = 4-batch evens + tail +
// 4-batch odds + tail + bias.
// ---------------------------------------------------------------------------
__global__ __launch_bounds__(1024) void snn_kernel(
    const float* __restrict__ cur1,
    const float* __restrict__ W2Tg, const float* __restrict__ WoTg,
    const float* __restrict__ W2, const float* __restrict__ Wo,
    const float* __restrict__ x, const float* __restrict__ W1,
    const float* __restrict__ b1,
    const float* __restrict__ b2, const float* __restrict__ bo,
    const int* __restrict__ nsp, float* __restrict__ out) {
  extern __shared__ float lds[];
  float* w2t = lds;                 // [256][128]
  float* wot = lds + H1 * H2;       // [128][10]

  const int tid = threadIdx.x;
  if (W2Tg != nullptr) {
    float4* dst = (float4*)w2t;
    const float4* src = (const float4*)W2Tg;
#pragma unroll
    for (int i = 0; i < 8; ++i) dst[tid + i * 1024] = src[tid + i * 1024];
    if (tid < 320) ((float4*)wot)[tid] = ((const float4*)WoTg)[tid];
  } else {
    for (int idx = tid; idx < H2 * H1; idx += 1024) {
      const int o = idx >> 8;
      const int j = idx & 255;
      w2t[j * H2 + o] = W2[idx];
    }
    for (int idx = tid; idx < NC * H2; idx += 1024) {
      const int o = idx >> 7;
      const int j = idx & 127;
      wot[j * NC + o] = Wo[idx];
    }
  }
  __syncthreads();

  const int w = tid >> 6;
  const int l = tid & 63;
  const int lo = (l < NC) ? l : 0;
  const float bb0 = b2[2 * l];
  const float bb1 = b2[2 * l + 1];
  const float bol = bo[lo];
  const float* w2l = w2t + 2 * l;   // lane's output pair within a row
  const int nsteps = *nsp;
  const v2f zz = {0.f, 0.f};

  for (int r = 0; r < 4; ++r) {
    const long b = (long)blockIdx.x * 64 + w * 4 + r;

    float c[4];
    if (cur1 != nullptr) {
#pragma unroll
      for (int i = 0; i < 4; ++i) c[i] = cur1[b * H1 + i * 64 + l];
    } else {
      const float* xr = x + b * IN_DIM;
#pragma unroll
      for (int i = 0; i < 4; ++i) {
        const int n = i * 64 + l;
        const float* wr = W1 + n * IN_DIM;
        float a = 0.f;
        for (int k = 0; k < IN_DIM; k += 4) {
          const float4 wv = *(const float4*)(wr + k);
          const float4 xv = *(const float4*)(xr + k);
          a = fmaf(wv.x, xv.x, a);
          a = fmaf(wv.y, xv.y, a);
          a = fmaf(wv.z, xv.z, a);
          a = fmaf(wv.w, xv.w, a);
        }
        c[i] = a + b1[n];
      }
    }

    float m1[4] = {0.f, 0.f, 0.f, 0.f};
    float sp1[4] = {0.f, 0.f, 0.f, 0.f};
    float m2a = 0.f, m2b = 0.f, sp2a = 0.f, sp2b = 0.f;
    float mo = 0.f, spo = 0.f, cnt = 0.f;

    for (int t = 0; t < nsteps; ++t) {
      // ---- layer 1 LIF ----
      unsigned long long mk[4];
#pragma unroll
      for (int i = 0; i < 4; ++i) {
        m1[i] = fmaf(0.5f, m1[i], c[i]) - sp1[i];
        const bool s = m1[i] > 1.0f;
        mk[i] = __ballot(s);
        sp1[i] = s ? 1.0f : 0.0f;
      }

      // ---- cur2 = s1 @ W2^T (+ b2): 4-deep pipelined sparse sum,
      //      register-zero dummies (no LDS cost for padding) ----
      v2f acc = zz;
#pragma unroll
      for (int i = 0; i < 4; ++i) {
        unsigned long long m = mk[i];
        if (!m) continue;
        const float* base = w2l + (i * 64) * H2;
        int j = __builtin_ctzll(m);
        m &= m - 1;
        v2f v0 = *(const v2f*)(base + j * H2);
        v2f v1 = zz, v2v = zz, v3 = zz;
        if (m) { j = __builtin_ctzll(m); m &= m - 1; v1  = *(const v2f*)(base + j * H2); }
        if (m) { j = __builtin_ctzll(m); m &= m - 1; v2v = *(const v2f*)(base + j * H2); }
        if (m) { j = __builtin_ctzll(m); m &= m - 1; v3  = *(const v2f*)(base + j * H2); }
        while (m) {
          v2f u0, u1 = zz, u2 = zz, u3 = zz;
          j = __builtin_ctzll(m);
          m &= m - 1;
          u0 = *(const v2f*)(base + j * H2);
          if (m) { j = __builtin_ctzll(m); m &= m - 1; u1 = *(const v2f*)(base + j * H2); }
          if (m) { j = __builtin_ctzll(m); m &= m - 1; u2 = *(const v2f*)(base + j * H2); }
          if (m) { j = __builtin_ctzll(m); m &= m - 1; u3 = *(const v2f*)(base + j * H2); }
          acc += v0;
          acc += v1;
          acc += v2v;
          acc += v3;
          v0 = u0; v1 = u1; v2v = u2; v3 = u3;
        }
        acc += v0;
        acc += v1;
        acc += v2v;
        acc += v3;
      }
      const float a0 = acc.x + bb0;
      const float a1 = acc.y + bb1;

      // ---- layer 2 LIF ----
      m2a = fmaf(0.5f, m2a, a0) - sp2a;
      m2b = fmaf(0.5f, m2b, a1) - sp2b;
      const bool sa = m2a > 1.0f;
      const bool sb = m2b > 1.0f;
      unsigned long long mA = __ballot(sa);
      unsigned long long mB = __ballot(sb);
      sp2a = sa ? 1.0f : 0.0f;
      sp2b = sb ? 1.0f : 0.0f;

      // ---- output layer: conditional 4-batch loads (even then odd),
      //      register-zero dummies, rare serial tail ----
      float va0 = 0.f, va1 = 0.f, va2 = 0.f, va3 = 0.f;
      float vb0 = 0.f, vb1 = 0.f, vb2 = 0.f, vb3 = 0.f;
      int j;
      if (mA) { j = __builtin_ctzll(mA); mA &= mA - 1; va0 = wot[(2 * j) * NC + lo]; }
      if (mA) { j = __builtin_ctzll(mA); mA &= mA - 1; va1 = wot[(2 * j) * NC + lo]; }
      if (mA) { j = __builtin_ctzll(mA); mA &= mA - 1; va2 = wot[(2 * j) * NC + lo]; }
      if (mA) { j = __builtin_ctzll(mA); mA &= mA - 1; va3 = wot[(2 * j) * NC + lo]; }
      if (mB) { j = __builtin_ctzll(mB); mB &= mB - 1; vb0 = wot[(2 * j + 1) * NC + lo]; }
      if (mB) { j = __builtin_ctzll(mB); mB &= mB - 1; vb1 = wot[(2 * j + 1) * NC + lo]; }
      if (mB) { j = __builtin_ctzll(mB); mB &= mB - 1; vb2 = wot[(2 * j + 1) * NC + lo]; }
      if (mB) { j = __builtin_ctzll(mB); mB &= mB - 1; vb3 = wot[(2 * j + 1) * NC + lo]; }

      float co = 0.f;
      co += va0; co += va1; co += va2; co += va3;
      while (mA) {
        j = __builtin_ctzll(mA);
        mA &= mA - 1;
        co += wot[(2 * j) * NC + lo];
      }
      co += vb0; co += vb1; co += vb2; co += vb3;
      while (mB) {
        j = __builtin_ctzll(mB);
        mB &= mB - 1;
        co += wot[(2 * j + 1) * NC + lo];
      }
      co += bol;

      // ---- output LIF + spike count ----
      mo = fmaf(0.5f, mo, co) - spo;
      const bool so = mo > 1.0f;
      spo = so ? 1.0f : 0.0f;
      cnt += spo;
    }

    if (l < NC) out[b * NC + l] = cnt;
  }
}

// ---------------------------------------------------------------------------
extern "C" void kernel_launch(void* const* d_in, const int* in_sizes, int n_in,
                              void* d_out, int out_size, void* d_ws,
                              size_t ws_size, hipStream_t stream) {
  const float* x  = (const float*)d_in[0];
  const float* W1 = (const float*)d_in[1];
  const float* b1 = (const float*)d_in[2];
  const float* W2 = (const float*)d_in[3];
  const float* b2 = (const float*)d_in[4];
  const float* Wo = (const float*)d_in[5];
  const float* bo = (const float*)d_in[6];
  const int* nsp  = (const int*)d_in[7];
  float* outp = (float*)d_out;

  const size_t cur1_bytes = (size_t)B_TOT * H1 * sizeof(float);
  const size_t w2t_bytes  = (size_t)H1 * H2 * sizeof(float);
  const size_t wot_bytes  = (size_t)H2 * NC * sizeof(float);

  float* cur1 = nullptr;
  float* W2Tg = nullptr;
  float* WoTg = nullptr;

  if (ws_size >= cur1_bytes) {
    cur1 = (float*)d_ws;
    gemm1_kernel<<<B_TOT / 16, 256, 0, stream>>>(x, W1, b1, cur1);
  }
  if (ws_size >= cur1_bytes + w2t_bytes + wot_bytes) {
    W2Tg = (float*)((char*)d_ws + cur1_bytes);
    WoTg = W2Tg + H1 * H2;
    transpose_kernel<<<(H2 * H1 + NC * H2 + 1023) / 1024, 1024, 0, stream>>>(
        W2, Wo, W2Tg, WoTg);
  }

  const size_t ldsB = (size_t)(H1 * H2 + H2 * NC) * sizeof(float);  // 133 KB
  hipFuncSetAttribute((const void*)snn_kernel,
                      hipFuncAttributeMaxDynamicSharedMemorySize, (int)ldsB);
  snn_kernel<<<256, 1024, ldsB, stream>>>(cur1, W2Tg, WoTg, W2, Wo, x, W1, b1,
                                          b2, bo, nsp, outp);
}